// Round 7
// baseline (456.697 us; speedup 1.0000x reference)
//
#include <hip/hip_runtime.h>
#include <hip/hip_bf16.h>

#define D_IN 128
#define SORT_CHUNK 4096
#define NBUCK 256

typedef __attribute__((ext_vector_type(8))) short bf16x8;
typedef __attribute__((ext_vector_type(4))) float f32x4;

// ======================= generic exclusive scan (1024/block) =======================

__global__ __launch_bounds__(256) void scan_block_sums(const int* __restrict__ in,
                                                       int* __restrict__ partial,
                                                       int M) {
    __shared__ int sdata[256];
    int b = blockIdx.x, t = threadIdx.x;
    int base = b * 1024 + t * 4;
    int s = 0;
#pragma unroll
    for (int i = 0; i < 4; ++i) {
        int idx = base + i;
        if (idx < M) s += in[idx];
    }
    sdata[t] = s;
    __syncthreads();
    for (int off = 128; off > 0; off >>= 1) {
        if (t < off) sdata[t] += sdata[t + off];
        __syncthreads();
    }
    if (t == 0) partial[b] = sdata[0];
}

__global__ void scan_partials(int* __restrict__ partial, int nb) {
    if (threadIdx.x == 0 && blockIdx.x == 0) {
        int run = 0;
        for (int i = 0; i < nb; ++i) {
            int t = partial[i];
            partial[i] = run;
            run += t;
        }
    }
}

__global__ __launch_bounds__(256) void scan_final(const int* __restrict__ in,
                                                  const int* __restrict__ partial,
                                                  int* __restrict__ outS,
                                                  int M) {
    __shared__ int sdata[256];
    int b = blockIdx.x, t = threadIdx.x;
    int base = b * 1024 + t * 4;
    int v[4];
    int s = 0;
#pragma unroll
    for (int i = 0; i < 4; ++i) {
        int idx = base + i;
        v[i] = (idx < M) ? in[idx] : 0;
        s += v[i];
    }
    sdata[t] = s;
    __syncthreads();
    for (int o = 1; o < 256; o <<= 1) {
        int tmp = 0;
        if (t >= o) tmp = sdata[t - o];
        __syncthreads();
        sdata[t] += tmp;
        __syncthreads();
    }
    int run = partial[b] + (sdata[t] - s);
#pragma unroll
    for (int i = 0; i < 4; ++i) {
        int idx = base + i;
        if (idx < M) outS[idx] = run;
        run += v[i];
    }
}

// ======================= two-pass bucket sort by dst =======================

__global__ __launch_bounds__(256) void bucket_hist_kernel(const int* __restrict__ dst,
                                                          int* __restrict__ bh,
                                                          long long E, int N, int nbe) {
    __shared__ int cnt[NBUCK];
    cnt[threadIdx.x] = 0;
    __syncthreads();
    long long base = (long long)blockIdx.x * SORT_CHUNK;
    long long end = base + SORT_CHUNK;
    if (end > E) end = E;
    for (long long i = base + threadIdx.x; i < end; i += 256) {
        int b = (int)(((long long)dst[i] << 8) / N);
        atomicAdd(&cnt[b], 1);
    }
    __syncthreads();
    bh[threadIdx.x * nbe + blockIdx.x] = cnt[threadIdx.x];
}

__global__ __launch_bounds__(256) void bucket_scatter_kernel(const int* __restrict__ src,
                                                             const int* __restrict__ dst,
                                                             const float* __restrict__ ew,
                                                             const int* __restrict__ S,
                                                             int2* __restrict__ tmp_edges,
                                                             int* __restrict__ tmp_dst,
                                                             long long E, int N, int nbe) {
    __shared__ int base_lds[NBUCK];
    __shared__ int cnt[NBUCK];
    base_lds[threadIdx.x] = S[threadIdx.x * nbe + blockIdx.x];
    cnt[threadIdx.x] = 0;
    __syncthreads();
    long long b0 = (long long)blockIdx.x * SORT_CHUNK;
    long long e1 = b0 + SORT_CHUNK;
    if (e1 > E) e1 = E;
    for (long long i = b0 + threadIdx.x; i < e1; i += 256) {
        int d = dst[i];
        int b = (int)(((long long)d << 8) / N);
        int p = base_lds[b] + atomicAdd(&cnt[b], 1);
        tmp_edges[p] = make_int2(src[i], __float_as_int(ew[i]));
        tmp_dst[p] = d;
    }
}

__global__ __launch_bounds__(256) void bucket_sort_kernel(const int* __restrict__ S,
                                                          const int2* __restrict__ tmp_edges,
                                                          const int* __restrict__ tmp_dst,
                                                          int2* __restrict__ edges,
                                                          int* __restrict__ hist,
                                                          int* __restrict__ off,
                                                          long long E, int N, int nbe) {
    __shared__ int cnt[512];
    __shared__ int tsum[256];
    __shared__ int pos[512];
    const int b = blockIdx.x, t = threadIdx.x;
    const int lo = (int)(((long long)b * N + 255) >> 8);
    const int hi = (int)(((long long)(b + 1) * N + 255) >> 8);
    const int start = S[b * nbe];
    const int end = (b == NBUCK - 1) ? (int)E : S[(b + 1) * nbe];

    cnt[t] = 0;
    cnt[t + 256] = 0;
    __syncthreads();
    for (int i = start + t; i < end; i += 256)
        atomicAdd(&cnt[tmp_dst[i] - lo], 1);
    __syncthreads();

    int a0 = cnt[2 * t], a1 = cnt[2 * t + 1];
    tsum[t] = a0 + a1;
    __syncthreads();
    for (int o = 1; o < 256; o <<= 1) {
        int v = (t >= o) ? tsum[t - o] : 0;
        __syncthreads();
        tsum[t] += v;
        __syncthreads();
    }
    int excl = tsum[t] - (a0 + a1);
    pos[2 * t]     = start + excl;
    pos[2 * t + 1] = start + excl + a0;

    int d0 = lo + 2 * t, d1 = lo + 2 * t + 1;
    if (d0 < hi) { hist[d0] = a0; off[d0] = start + excl + a0; }
    if (d1 < hi) { hist[d1] = a1; off[d1] = start + excl + a0 + a1; }
    __syncthreads();

    for (int i = start + t; i < end; i += 256) {
        int d = tmp_dst[i] - lo;
        int r = atomicAdd(&pos[d], 1);
        edges[r] = tmp_edges[i];
    }
}

// ======================= dtype conversions =======================

__global__ __launch_bounds__(256) void conv_x_kernel(const float* __restrict__ x,
                                                     __hip_bfloat16* __restrict__ xb,
                                                     long long total4) {
    long long i = (long long)blockIdx.x * 256 + threadIdx.x;
    if (i >= total4) return;
    float4 v = reinterpret_cast<const float4*>(x)[i];
    union { ushort4 u; __hip_bfloat162 h2[2]; } o;
    o.h2[0] = __float22bfloat162_rn(make_float2(v.x, v.y));
    o.h2[1] = __float22bfloat162_rn(make_float2(v.z, v.w));
    reinterpret_cast<ushort4*>(xb)[i] = o.u;
}

// Wt[j][k] = (k<128 ? Wrel[k][j] : Wroot[k-128][j]), bf16
template <int DOUT>
__global__ __launch_bounds__(256) void conv_w_kernel(const float* __restrict__ Wrel,
                                                     const float* __restrict__ Wroot,
                                                     __hip_bfloat16* __restrict__ Wt) {
    int idx = blockIdx.x * 256 + threadIdx.x;
    if (idx >= DOUT * 256) return;
    int j = idx >> 8;
    int k = idx & 255;
    float v = (k < 128) ? Wrel[(size_t)k * DOUT + j] : Wroot[(size_t)(k - 128) * DOUT + j];
    Wt[idx] = __float2bfloat16(v);
}

// =============== fused layer: gather+mean -> LDS, then MFMA GEMM ===============
// Block: 512 thr = 8 waves; owns 128 output rows (one panel).
// Phase 1: each wave aggregates 16 nodes into LDS A-tile (bf16, row stride 272 B
//          -> 2-way bank aliasing on b128 reads = free).
// Phase 2: out[rows][:] = A_lds @ Wt[:, 0:128]^T + in @ Wt[:, 128:256]^T + bias.
// Wave tiles: 2 (row) x 4 (col) of 64 x (DOUT/4).
template <int DOUT, bool OUT_BF16>
__global__ __launch_bounds__(512, 4) void fused_layer(const __hip_bfloat16* __restrict__ inb,
                                                      const int2* __restrict__ edges,
                                                      const int* __restrict__ off,
                                                      const int* __restrict__ hist,
                                                      const __hip_bfloat16* __restrict__ Wt,
                                                      const float* __restrict__ bias,
                                                      void* __restrict__ outp,
                                                      int N) {
    __shared__ __align__(16) short As[128 * 136];   // 128 rows x 272 B (128 bf16 + pad)

    const int tid = threadIdx.x;
    const int w = tid >> 6;
    const int lane = tid & 63;
    const int rowg0 = blockIdx.x * 128;

    // ---- phase 1: gather + mean into LDS ----
    const __hip_bfloat162* f2 = reinterpret_cast<const __hip_bfloat162*>(inb);
    for (int i = 0; i < 16; ++i) {
        int rloc = w * 16 + i;
        int node = rowg0 + rloc;
        float ax = 0.f, ay = 0.f;
        if (node < N) {
            int cnt = hist[node];
            int end = off[node];
            int start = end - cnt;
            float inv = 1.0f / fmaxf((float)cnt, 1.0f);
            int e = start;
            for (; e + 7 < end; e += 8) {
                int2 ed[8];
#pragma unroll
                for (int j = 0; j < 8; ++j) ed[j] = edges[e + j];
#pragma unroll
                for (int j = 0; j < 8; ++j) {
                    float wgt = __int_as_float(ed[j].y);
                    float2 v = __bfloat1622float2(f2[(size_t)ed[j].x * 64 + lane]);
                    ax += wgt * v.x;
                    ay += wgt * v.y;
                }
            }
            for (; e < end; ++e) {
                int2 ed = edges[e];
                float wgt = __int_as_float(ed.y);
                float2 v = __bfloat1622float2(f2[(size_t)ed.x * 64 + lane]);
                ax += wgt * v.x;
                ay += wgt * v.y;
            }
            ax *= inv;
            ay *= inv;
        }
        *reinterpret_cast<__hip_bfloat162*>(&As[rloc * 136 + lane * 2]) =
            __float22bfloat162_rn(make_float2(ax, ay));
    }
    __syncthreads();

    // ---- phase 2: GEMM ----
    constexpr int NI = DOUT / 64;      // col 16-tiles per wave (4 or 2)
    const int wr = w >> 2;             // row half 0..1
    const int wc = w & 3;              // col quarter 0..3
    const int lr = lane & 15;
    const int lk = lane >> 4;
    const int nbase = wc * (DOUT / 4);

    const short* wrow[NI];
#pragma unroll
    for (int ni = 0; ni < NI; ++ni)
        wrow[ni] = (const short*)Wt + (size_t)(nbase + ni * 16 + lr) * 256 + lk * 8;

    int rl[4];
    const short* xrow[4];
#pragma unroll
    for (int mi = 0; mi < 4; ++mi) {
        rl[mi] = wr * 64 + mi * 16 + lr;
        int row = rowg0 + rl[mi];
        int rc = row < N ? row : N - 1;
        xrow[mi] = (const short*)inb + (size_t)rc * 128 + lk * 8;
    }

    f32x4 zero = {0.f, 0.f, 0.f, 0.f};
    f32x4 acc[4][NI];
#pragma unroll
    for (int mi = 0; mi < 4; ++mi)
#pragma unroll
        for (int ni = 0; ni < NI; ++ni) acc[mi][ni] = zero;

    // k = 0..127: A_rel from LDS
#pragma unroll
    for (int kk = 0; kk < 4; ++kk) {
        bf16x8 a[4], b[NI];
#pragma unroll
        for (int mi = 0; mi < 4; ++mi)
            a[mi] = *reinterpret_cast<const bf16x8*>(&As[rl[mi] * 136 + kk * 32 + lk * 8]);
#pragma unroll
        for (int ni = 0; ni < NI; ++ni)
            b[ni] = *reinterpret_cast<const bf16x8*>(wrow[ni] + kk * 32);
#pragma unroll
        for (int mi = 0; mi < 4; ++mi)
#pragma unroll
            for (int ni = 0; ni < NI; ++ni)
                acc[mi][ni] = __builtin_amdgcn_mfma_f32_16x16x32_bf16(a[mi], b[ni], acc[mi][ni], 0, 0, 0);
    }
    // k = 128..255: A_root from global
#pragma unroll
    for (int kk = 4; kk < 8; ++kk) {
        bf16x8 a[4], b[NI];
#pragma unroll
        for (int mi = 0; mi < 4; ++mi)
            a[mi] = *reinterpret_cast<const bf16x8*>(xrow[mi] + (kk - 4) * 32);
#pragma unroll
        for (int ni = 0; ni < NI; ++ni)
            b[ni] = *reinterpret_cast<const bf16x8*>(wrow[ni] + kk * 32);
#pragma unroll
        for (int mi = 0; mi < 4; ++mi)
#pragma unroll
            for (int ni = 0; ni < NI; ++ni)
                acc[mi][ni] = __builtin_amdgcn_mfma_f32_16x16x32_bf16(a[mi], b[ni], acc[mi][ni], 0, 0, 0);
    }

    // epilogue
#pragma unroll
    for (int mi = 0; mi < 4; ++mi)
#pragma unroll
        for (int ni = 0; ni < NI; ++ni) {
            int col = nbase + ni * 16 + lr;
            float bv = bias[col];
#pragma unroll
            for (int rr = 0; rr < 4; ++rr) {
                int row = rowg0 + wr * 64 + mi * 16 + lk * 4 + rr;
                if (row < N) {
                    float v = acc[mi][ni][rr] + bv;
                    if (OUT_BF16)
                        ((__hip_bfloat16*)outp)[(size_t)row * DOUT + col] = __float2bfloat16(v);
                    else
                        ((float*)outp)[(size_t)row * DOUT + col] = v;
                }
            }
        }
}

// ======================= launch =======================

extern "C" void kernel_launch(void* const* d_in, const int* in_sizes, int n_in,
                              void* d_out, int out_size, void* d_ws, size_t ws_size,
                              hipStream_t stream) {
    const float* x      = (const float*)d_in[0];
    const int*   ei     = (const int*)d_in[1];
    const float* ew     = (const float*)d_in[2];
    const float* Wrel1  = (const float*)d_in[3];
    const float* b1     = (const float*)d_in[4];
    const float* Wroot1 = (const float*)d_in[5];
    const float* Wrel2  = (const float*)d_in[6];
    const float* b2     = (const float*)d_in[7];
    const float* Wroot2 = (const float*)d_in[8];
    float* out = (float*)d_out;

    const int N = in_sizes[0] / D_IN;
    const long long E = in_sizes[2];
    const int* src = ei;
    const int* dst = ei + E;

    const int nbe = (int)((E + SORT_CHUNK - 1) / SORT_CHUNK);
    const int M = nbe * NBUCK;
    const int nbM = (M + 1023) / 1024;

    // workspace layout:
    // [hist N][off N][part 128][edges E int2]
    // [scratchA N*128 bf16][xb N*128 bf16][scratchB N*128 bf16][hb N*128 bf16][Wt1][Wt2]
    int* hist = (int*)d_ws;
    int* off  = hist + N;
    int* part = off + N;
    int2* edges = (int2*)(part + 128);
    __hip_bfloat16* scrA  = (__hip_bfloat16*)(edges + E);
    __hip_bfloat16* xb    = scrA + (size_t)N * D_IN;
    __hip_bfloat16* scrB  = xb   + (size_t)N * D_IN;
    __hip_bfloat16* hb    = scrB + (size_t)N * D_IN;
    __hip_bfloat16* Wt1   = hb   + (size_t)N * D_IN;
    __hip_bfloat16* Wt2   = Wt1  + 128 * 256;

    // transient sort buffers overlapped into scratch regions:
    int* bh      = (int*)scrA;
    int* S       = bh + M;
    int* tmp_dst = S + M;
    int2* tmp_edges = (int2*)scrB;

    // ---- sort edges by dst ----
    bucket_hist_kernel<<<nbe, 256, 0, stream>>>(dst, bh, E, N, nbe);
    scan_block_sums<<<nbM, 256, 0, stream>>>(bh, part, M);
    scan_partials<<<1, 64, 0, stream>>>(part, nbM);
    scan_final<<<nbM, 256, 0, stream>>>(bh, part, S, M);
    bucket_scatter_kernel<<<nbe, 256, 0, stream>>>(src, dst, ew, S, tmp_edges, tmp_dst, E, N, nbe);
    bucket_sort_kernel<<<NBUCK, 256, 0, stream>>>(S, tmp_edges, tmp_dst, edges, hist, off, E, N, nbe);

    // ---- conversions ----
    {
        long long total4 = (long long)N * D_IN / 4;
        conv_x_kernel<<<(int)((total4 + 255) / 256), 256, 0, stream>>>(x, xb, total4);
        conv_w_kernel<128><<<(128 * 256 + 255) / 256, 256, 0, stream>>>(Wrel1, Wroot1, Wt1);
        conv_w_kernel<256><<<(256 * 256 + 255) / 256, 256, 0, stream>>>(Wrel2, Wroot2, Wt2);
    }

    const int gx = (N + 127) / 128;

    // ---- layer 1 (fused aggregate + GEMM) -> hb (bf16) ----
    fused_layer<128, true><<<gx, 512, 0, stream>>>(xb, edges, off, hist, Wt1, b1, hb, N);

    // ---- layer 2 (fused aggregate + GEMM) -> out (fp32) ----
    fused_layer<256, false><<<gx, 512, 0, stream>>>(hb, edges, off, hist, Wt2, b2, out, N);
}

// Round 8
// 331.564 us; speedup vs baseline: 1.3774x; 1.3774x over previous
//
#include <hip/hip_runtime.h>
#include <hip/hip_bf16.h>

#define D_IN 128
#define SORT_CHUNK 4096
#define NBUCK 256

typedef __attribute__((ext_vector_type(8))) short bf16x8;
typedef __attribute__((ext_vector_type(8))) unsigned short u16x8;
typedef __attribute__((ext_vector_type(4))) float f32x4;

// ======================= generic exclusive scan (1024/block) =======================

__global__ __launch_bounds__(256) void scan_block_sums(const int* __restrict__ in,
                                                       int* __restrict__ partial,
                                                       int M) {
    __shared__ int sdata[256];
    int b = blockIdx.x, t = threadIdx.x;
    int base = b * 1024 + t * 4;
    int s = 0;
#pragma unroll
    for (int i = 0; i < 4; ++i) {
        int idx = base + i;
        if (idx < M) s += in[idx];
    }
    sdata[t] = s;
    __syncthreads();
    for (int off = 128; off > 0; off >>= 1) {
        if (t < off) sdata[t] += sdata[t + off];
        __syncthreads();
    }
    if (t == 0) partial[b] = sdata[0];
}

__global__ void scan_partials(int* __restrict__ partial, int nb) {
    if (threadIdx.x == 0 && blockIdx.x == 0) {
        int run = 0;
        for (int i = 0; i < nb; ++i) {
            int t = partial[i];
            partial[i] = run;
            run += t;
        }
    }
}

__global__ __launch_bounds__(256) void scan_final(const int* __restrict__ in,
                                                  const int* __restrict__ partial,
                                                  int* __restrict__ outS,
                                                  int M) {
    __shared__ int sdata[256];
    int b = blockIdx.x, t = threadIdx.x;
    int base = b * 1024 + t * 4;
    int v[4];
    int s = 0;
#pragma unroll
    for (int i = 0; i < 4; ++i) {
        int idx = base + i;
        v[i] = (idx < M) ? in[idx] : 0;
        s += v[i];
    }
    sdata[t] = s;
    __syncthreads();
    for (int o = 1; o < 256; o <<= 1) {
        int tmp = 0;
        if (t >= o) tmp = sdata[t - o];
        __syncthreads();
        sdata[t] += tmp;
        __syncthreads();
    }
    int run = partial[b] + (sdata[t] - s);
#pragma unroll
    for (int i = 0; i < 4; ++i) {
        int idx = base + i;
        if (idx < M) outS[idx] = run;
        run += v[i];
    }
}

// ======================= two-pass bucket sort by dst =======================

__global__ __launch_bounds__(256) void bucket_hist_kernel(const int* __restrict__ dst,
                                                          int* __restrict__ bh,
                                                          long long E, int N, int nbe) {
    __shared__ int cnt[NBUCK];
    cnt[threadIdx.x] = 0;
    __syncthreads();
    long long base = (long long)blockIdx.x * SORT_CHUNK;
    long long end = base + SORT_CHUNK;
    if (end > E) end = E;
    for (long long i = base + threadIdx.x; i < end; i += 256) {
        int b = (int)(((long long)dst[i] << 8) / N);
        atomicAdd(&cnt[b], 1);
    }
    __syncthreads();
    bh[threadIdx.x * nbe + blockIdx.x] = cnt[threadIdx.x];
}

__global__ __launch_bounds__(256) void bucket_scatter_kernel(const int* __restrict__ src,
                                                             const int* __restrict__ dst,
                                                             const float* __restrict__ ew,
                                                             const int* __restrict__ S,
                                                             int2* __restrict__ tmp_edges,
                                                             int* __restrict__ tmp_dst,
                                                             long long E, int N, int nbe) {
    __shared__ int base_lds[NBUCK];
    __shared__ int cnt[NBUCK];
    base_lds[threadIdx.x] = S[threadIdx.x * nbe + blockIdx.x];
    cnt[threadIdx.x] = 0;
    __syncthreads();
    long long b0 = (long long)blockIdx.x * SORT_CHUNK;
    long long e1 = b0 + SORT_CHUNK;
    if (e1 > E) e1 = E;
    for (long long i = b0 + threadIdx.x; i < e1; i += 256) {
        int d = dst[i];
        int b = (int)(((long long)d << 8) / N);
        int p = base_lds[b] + atomicAdd(&cnt[b], 1);
        tmp_edges[p] = make_int2(src[i], __float_as_int(ew[i]));
        tmp_dst[p] = d;
    }
}

__global__ __launch_bounds__(256) void bucket_sort_kernel(const int* __restrict__ S,
                                                          const int2* __restrict__ tmp_edges,
                                                          const int* __restrict__ tmp_dst,
                                                          int2* __restrict__ edges,
                                                          int* __restrict__ hist,
                                                          int* __restrict__ off,
                                                          long long E, int N, int nbe) {
    __shared__ int cnt[512];
    __shared__ int tsum[256];
    __shared__ int pos[512];
    const int b = blockIdx.x, t = threadIdx.x;
    const int lo = (int)(((long long)b * N + 255) >> 8);
    const int hi = (int)(((long long)(b + 1) * N + 255) >> 8);
    const int start = S[b * nbe];
    const int end = (b == NBUCK - 1) ? (int)E : S[(b + 1) * nbe];

    cnt[t] = 0;
    cnt[t + 256] = 0;
    __syncthreads();
    for (int i = start + t; i < end; i += 256)
        atomicAdd(&cnt[tmp_dst[i] - lo], 1);
    __syncthreads();

    int a0 = cnt[2 * t], a1 = cnt[2 * t + 1];
    tsum[t] = a0 + a1;
    __syncthreads();
    for (int o = 1; o < 256; o <<= 1) {
        int v = (t >= o) ? tsum[t - o] : 0;
        __syncthreads();
        tsum[t] += v;
        __syncthreads();
    }
    int excl = tsum[t] - (a0 + a1);
    pos[2 * t]     = start + excl;
    pos[2 * t + 1] = start + excl + a0;

    int d0 = lo + 2 * t, d1 = lo + 2 * t + 1;
    if (d0 < hi) { hist[d0] = a0; off[d0] = start + excl + a0; }
    if (d1 < hi) { hist[d1] = a1; off[d1] = start + excl + a0 + a1; }
    __syncthreads();

    for (int i = start + t; i < end; i += 256) {
        int d = tmp_dst[i] - lo;
        int r = atomicAdd(&pos[d], 1);
        edges[r] = tmp_edges[i];
    }
}

// ======================= dtype conversions =======================

__global__ __launch_bounds__(256) void conv_x_kernel(const float* __restrict__ x,
                                                     __hip_bfloat16* __restrict__ xb,
                                                     long long total4) {
    long long i = (long long)blockIdx.x * 256 + threadIdx.x;
    if (i >= total4) return;
    float4 v = reinterpret_cast<const float4*>(x)[i];
    union { ushort4 u; __hip_bfloat162 h2[2]; } o;
    o.h2[0] = __float22bfloat162_rn(make_float2(v.x, v.y));
    o.h2[1] = __float22bfloat162_rn(make_float2(v.z, v.w));
    reinterpret_cast<ushort4*>(xb)[i] = o.u;
}

// Wt[j][k] = (k<128 ? Wrel[k][j] : Wroot[k-128][j]), bf16
template <int DOUT>
__global__ __launch_bounds__(256) void conv_w_kernel(const float* __restrict__ Wrel,
                                                     const float* __restrict__ Wroot,
                                                     __hip_bfloat16* __restrict__ Wt) {
    int idx = blockIdx.x * 256 + threadIdx.x;
    if (idx >= DOUT * 256) return;
    int j = idx >> 8;
    int k = idx & 255;
    float v = (k < 128) ? Wrel[(size_t)k * DOUT + j] : Wroot[(size_t)(k - 128) * DOUT + j];
    Wt[idx] = __float2bfloat16(v);
}

// =============== segmented aggregation v2: 4 edge-slots/wave, 16B/lane ===============
// One wave per node. lane group g=lane>>4 owns edge slot (start+g, +4, +8, ...);
// 16 lanes x 16B (u16x8) cover one 256B feature row. 2-deep unroll -> 8 rows in
// flight per wave. Final: shfl_xor(16),(32) tree-reduce across groups; group 0 stores.
__global__ __launch_bounds__(256) void aggregate_kernel(const __hip_bfloat16* __restrict__ featb,
                                                        const int2* __restrict__ edges,
                                                        const int* __restrict__ off,
                                                        const int* __restrict__ hist,
                                                        __hip_bfloat16* __restrict__ aggb,
                                                        int N) {
    int node = blockIdx.x * 4 + (threadIdx.x >> 6);
    if (node >= N) return;
    const int lane = threadIdx.x & 63;
    const int g = lane >> 4;        // edge slot 0..3
    const int sub = lane & 15;      // 8-feature chunk
    const int cnt = hist[node];
    const int end = off[node];      // inclusive prefix = segment end
    const int start = end - cnt;
    const float inv = 1.0f / fmaxf((float)cnt, 1.0f);

    const ushort* fb = (const ushort*)featb;
    float acc[8] = {0.f, 0.f, 0.f, 0.f, 0.f, 0.f, 0.f, 0.f};

    int e = start + g;
    for (; e + 4 < end; e += 8) {
        int2 e0 = edges[e];
        int2 e1 = edges[e + 4];
        float w0 = __int_as_float(e0.y);
        float w1 = __int_as_float(e1.y);
        u16x8 r0 = *reinterpret_cast<const u16x8*>(fb + (size_t)e0.x * 128 + sub * 8);
        u16x8 r1 = *reinterpret_cast<const u16x8*>(fb + (size_t)e1.x * 128 + sub * 8);
#pragma unroll
        for (int j = 0; j < 8; ++j) {
            acc[j] += w0 * __int_as_float((unsigned)r0[j] << 16)
                    + w1 * __int_as_float((unsigned)r1[j] << 16);
        }
    }
    if (e < end) {
        int2 e0 = edges[e];
        float w0 = __int_as_float(e0.y);
        u16x8 r0 = *reinterpret_cast<const u16x8*>(fb + (size_t)e0.x * 128 + sub * 8);
#pragma unroll
        for (int j = 0; j < 8; ++j)
            acc[j] += w0 * __int_as_float((unsigned)r0[j] << 16);
    }

    // cross-group tree reduce (groups differ in lane bits 4,5)
#pragma unroll
    for (int j = 0; j < 8; ++j) {
        acc[j] += __shfl_xor(acc[j], 16, 64);
        acc[j] += __shfl_xor(acc[j], 32, 64);
    }

    if (g == 0) {
        union { u16x8 u; __hip_bfloat162 h2[4]; } o;
#pragma unroll
        for (int j = 0; j < 4; ++j)
            o.h2[j] = __float22bfloat162_rn(make_float2(acc[2 * j] * inv, acc[2 * j + 1] * inv));
        *reinterpret_cast<u16x8*>((ushort*)aggb + (size_t)node * 128 + sub * 8) = o.u;
    }
}

// =============== MFMA GEMM v2: 128x128 block tile, 64x64 wave tile ===============
// out = [Arel|Aroot] @ Wt^T + bias.  Wt: [DOUT][256] bf16.
// 1D grid, y(col-strip)-fastest + bijective XCD swizzle for A-panel L2 reuse.
template <int DOUT, bool OUT_BF16>
__global__ __launch_bounds__(256) void gemm_mfma2(const __hip_bfloat16* __restrict__ Arel,
                                                  const __hip_bfloat16* __restrict__ Aroot,
                                                  const __hip_bfloat16* __restrict__ Wt,
                                                  const float* __restrict__ bias,
                                                  void* __restrict__ outp,
                                                  int M) {
    constexpr int NY = DOUT / 128;
    const int nb = gridDim.x;
    const int orig = blockIdx.x;
    const int xcd = orig & 7;
    const int lid = orig >> 3;
    const int q = nb >> 3, r = nb & 7;
    const int wgid = (xcd < r ? xcd * (q + 1) : r * (q + 1) + (xcd - r) * q) + lid;

    const int ty = wgid % NY;
    const int tx = wgid / NY;
    const int tid = threadIdx.x;
    const int lane = tid & 63;
    const int wave = tid >> 6;
    const int lr = lane & 15;
    const int lk = lane >> 4;
    const int mbase = tx * 128 + (wave >> 1) * 64;
    const int nbase = ty * 128 + (wave & 1) * 64;

    const short* arow[4];
    const short* xrow[4];
#pragma unroll
    for (int mi = 0; mi < 4; ++mi) {
        int row = mbase + mi * 16 + lr;
        int rc = row < M ? row : M - 1;
        arow[mi] = (const short*)Arel  + (size_t)rc * 128 + lk * 8;
        xrow[mi] = (const short*)Aroot + (size_t)rc * 128 + lk * 8;
    }
    const short* wrow[4];
#pragma unroll
    for (int ni = 0; ni < 4; ++ni)
        wrow[ni] = (const short*)Wt + (size_t)(nbase + ni * 16 + lr) * 256 + lk * 8;

    f32x4 zero = {0.f, 0.f, 0.f, 0.f};
    f32x4 acc[4][4];
#pragma unroll
    for (int mi = 0; mi < 4; ++mi)
#pragma unroll
        for (int ni = 0; ni < 4; ++ni) acc[mi][ni] = zero;

#pragma unroll
    for (int kk = 0; kk < 8; ++kk) {
        bf16x8 a[4], b[4];
#pragma unroll
        for (int mi = 0; mi < 4; ++mi)
            a[mi] = (kk < 4)
                ? *reinterpret_cast<const bf16x8*>(arow[mi] + kk * 32)
                : *reinterpret_cast<const bf16x8*>(xrow[mi] + (kk - 4) * 32);
#pragma unroll
        for (int ni = 0; ni < 4; ++ni)
            b[ni] = *reinterpret_cast<const bf16x8*>(wrow[ni] + kk * 32);
#pragma unroll
        for (int mi = 0; mi < 4; ++mi)
#pragma unroll
            for (int ni = 0; ni < 4; ++ni)
                acc[mi][ni] = __builtin_amdgcn_mfma_f32_16x16x32_bf16(a[mi], b[ni], acc[mi][ni], 0, 0, 0);
    }

#pragma unroll
    for (int mi = 0; mi < 4; ++mi)
#pragma unroll
        for (int ni = 0; ni < 4; ++ni) {
            int col = nbase + ni * 16 + lr;
            float bv = bias[col];
#pragma unroll
            for (int rr = 0; rr < 4; ++rr) {
                int row = mbase + mi * 16 + lk * 4 + rr;
                if (row < M) {
                    float v = acc[mi][ni][rr] + bv;
                    if (OUT_BF16)
                        ((__hip_bfloat16*)outp)[(size_t)row * DOUT + col] = __float2bfloat16(v);
                    else
                        __builtin_nontemporal_store(v, (float*)outp + (size_t)row * DOUT + col);
                }
            }
        }
}

// ======================= launch =======================

extern "C" void kernel_launch(void* const* d_in, const int* in_sizes, int n_in,
                              void* d_out, int out_size, void* d_ws, size_t ws_size,
                              hipStream_t stream) {
    const float* x      = (const float*)d_in[0];
    const int*   ei     = (const int*)d_in[1];
    const float* ew     = (const float*)d_in[2];
    const float* Wrel1  = (const float*)d_in[3];
    const float* b1     = (const float*)d_in[4];
    const float* Wroot1 = (const float*)d_in[5];
    const float* Wrel2  = (const float*)d_in[6];
    const float* b2     = (const float*)d_in[7];
    const float* Wroot2 = (const float*)d_in[8];
    float* out = (float*)d_out;

    const int N = in_sizes[0] / D_IN;
    const long long E = in_sizes[2];
    const int* src = ei;
    const int* dst = ei + E;

    const int nbe = (int)((E + SORT_CHUNK - 1) / SORT_CHUNK);
    const int M = nbe * NBUCK;
    const int nbM = (M + 1023) / 1024;

    int* hist = (int*)d_ws;
    int* off  = hist + N;
    int* part = off + N;
    int2* edges = (int2*)(part + 128);
    __hip_bfloat16* agg1b = (__hip_bfloat16*)(edges + E);
    __hip_bfloat16* xb    = agg1b + (size_t)N * D_IN;
    __hip_bfloat16* agg2b = xb    + (size_t)N * D_IN;
    __hip_bfloat16* hb    = agg2b + (size_t)N * D_IN;
    __hip_bfloat16* Wt1   = hb    + (size_t)N * D_IN;
    __hip_bfloat16* Wt2   = Wt1   + 128 * 256;

    // transient sort buffers overlapped into agg regions (consumed before aggregates run)
    int* bh      = (int*)agg1b;
    int* S       = bh + M;
    int* tmp_dst = S + M;
    int2* tmp_edges = (int2*)agg2b;

    // ---- sort edges by dst ----
    bucket_hist_kernel<<<nbe, 256, 0, stream>>>(dst, bh, E, N, nbe);
    scan_block_sums<<<nbM, 256, 0, stream>>>(bh, part, M);
    scan_partials<<<1, 64, 0, stream>>>(part, nbM);
    scan_final<<<nbM, 256, 0, stream>>>(bh, part, S, M);
    bucket_scatter_kernel<<<nbe, 256, 0, stream>>>(src, dst, ew, S, tmp_edges, tmp_dst, E, N, nbe);
    bucket_sort_kernel<<<NBUCK, 256, 0, stream>>>(S, tmp_edges, tmp_dst, edges, hist, off, E, N, nbe);

    // ---- conversions ----
    {
        long long total4 = (long long)N * D_IN / 4;
        conv_x_kernel<<<(int)((total4 + 255) / 256), 256, 0, stream>>>(x, xb, total4);
        conv_w_kernel<128><<<(128 * 256 + 255) / 256, 256, 0, stream>>>(Wrel1, Wroot1, Wt1);
        conv_w_kernel<256><<<(256 * 256 + 255) / 256, 256, 0, stream>>>(Wrel2, Wroot2, Wt2);
    }

    const int ab = (N + 3) / 4;
    const int gx = (N + 127) / 128;

    // ---- layer 1 ----
    aggregate_kernel<<<ab, 256, 0, stream>>>(xb, edges, off, hist, agg1b, N);
    gemm_mfma2<128, true><<<gx * 1, 256, 0, stream>>>(agg1b, xb, Wt1, b1, hb, N);

    // ---- layer 2 ----
    aggregate_kernel<<<ab, 256, 0, stream>>>(hb, edges, off, hist, agg2b, N);
    gemm_mfma2<256, false><<<gx * 2, 256, 0, stream>>>(agg2b, hb, Wt2, b2, out, N);
}

// Round 9
// 325.322 us; speedup vs baseline: 1.4038x; 1.0192x over previous
//
#include <hip/hip_runtime.h>
#include <hip/hip_bf16.h>

#define D_IN 128
#define SORT_CHUNK 4096
#define NBUCK 256

typedef __attribute__((ext_vector_type(8))) short bf16x8;
typedef __attribute__((ext_vector_type(8))) unsigned short u16x8;
typedef __attribute__((ext_vector_type(4))) float f32x4;

// ======================= generic exclusive scan (1024/block) =======================

__global__ __launch_bounds__(256) void scan_block_sums(const int* __restrict__ in,
                                                       int* __restrict__ partial,
                                                       int M) {
    __shared__ int sdata[256];
    int b = blockIdx.x, t = threadIdx.x;
    int base = b * 1024 + t * 4;
    int s = 0;
#pragma unroll
    for (int i = 0; i < 4; ++i) {
        int idx = base + i;
        if (idx < M) s += in[idx];
    }
    sdata[t] = s;
    __syncthreads();
    for (int off = 128; off > 0; off >>= 1) {
        if (t < off) sdata[t] += sdata[t + off];
        __syncthreads();
    }
    if (t == 0) partial[b] = sdata[0];
}

__global__ void scan_partials(int* __restrict__ partial, int nb) {
    if (threadIdx.x == 0 && blockIdx.x == 0) {
        int run = 0;
        for (int i = 0; i < nb; ++i) {
            int t = partial[i];
            partial[i] = run;
            run += t;
        }
    }
}

__global__ __launch_bounds__(256) void scan_final(const int* __restrict__ in,
                                                  const int* __restrict__ partial,
                                                  int* __restrict__ outS,
                                                  int M) {
    __shared__ int sdata[256];
    int b = blockIdx.x, t = threadIdx.x;
    int base = b * 1024 + t * 4;
    int v[4];
    int s = 0;
#pragma unroll
    for (int i = 0; i < 4; ++i) {
        int idx = base + i;
        v[i] = (idx < M) ? in[idx] : 0;
        s += v[i];
    }
    sdata[t] = s;
    __syncthreads();
    for (int o = 1; o < 256; o <<= 1) {
        int tmp = 0;
        if (t >= o) tmp = sdata[t - o];
        __syncthreads();
        sdata[t] += tmp;
        __syncthreads();
    }
    int run = partial[b] + (sdata[t] - s);
#pragma unroll
    for (int i = 0; i < 4; ++i) {
        int idx = base + i;
        if (idx < M) outS[idx] = run;
        run += v[i];
    }
}

// ======================= two-pass bucket sort by dst =======================

__global__ __launch_bounds__(256) void bucket_hist_kernel(const int* __restrict__ dst,
                                                          int* __restrict__ bh,
                                                          long long E, int N, int nbe) {
    __shared__ int cnt[NBUCK];
    cnt[threadIdx.x] = 0;
    __syncthreads();
    long long base = (long long)blockIdx.x * SORT_CHUNK;
    long long end = base + SORT_CHUNK;
    if (end > E) end = E;
    for (long long i = base + threadIdx.x; i < end; i += 256) {
        int b = (int)(((long long)dst[i] << 8) / N);
        atomicAdd(&cnt[b], 1);
    }
    __syncthreads();
    bh[threadIdx.x * nbe + blockIdx.x] = cnt[threadIdx.x];
}

__global__ __launch_bounds__(256) void bucket_scatter_kernel(const int* __restrict__ src,
                                                             const int* __restrict__ dst,
                                                             const float* __restrict__ ew,
                                                             const int* __restrict__ S,
                                                             int2* __restrict__ tmp_edges,
                                                             int* __restrict__ tmp_dst,
                                                             long long E, int N, int nbe) {
    __shared__ int base_lds[NBUCK];
    __shared__ int cnt[NBUCK];
    base_lds[threadIdx.x] = S[threadIdx.x * nbe + blockIdx.x];
    cnt[threadIdx.x] = 0;
    __syncthreads();
    long long b0 = (long long)blockIdx.x * SORT_CHUNK;
    long long e1 = b0 + SORT_CHUNK;
    if (e1 > E) e1 = E;
    for (long long i = b0 + threadIdx.x; i < e1; i += 256) {
        int d = dst[i];
        int b = (int)(((long long)d << 8) / N);
        int p = base_lds[b] + atomicAdd(&cnt[b], 1);
        tmp_edges[p] = make_int2(src[i], __float_as_int(ew[i]));
        tmp_dst[p] = d;
    }
}

__global__ __launch_bounds__(256) void bucket_sort_kernel(const int* __restrict__ S,
                                                          const int2* __restrict__ tmp_edges,
                                                          const int* __restrict__ tmp_dst,
                                                          int2* __restrict__ edges,
                                                          int* __restrict__ hist,
                                                          int* __restrict__ off,
                                                          long long E, int N, int nbe) {
    __shared__ int cnt[512];
    __shared__ int tsum[256];
    __shared__ int pos[512];
    const int b = blockIdx.x, t = threadIdx.x;
    const int lo = (int)(((long long)b * N + 255) >> 8);
    const int hi = (int)(((long long)(b + 1) * N + 255) >> 8);
    const int start = S[b * nbe];
    const int end = (b == NBUCK - 1) ? (int)E : S[(b + 1) * nbe];

    cnt[t] = 0;
    cnt[t + 256] = 0;
    __syncthreads();
    for (int i = start + t; i < end; i += 256)
        atomicAdd(&cnt[tmp_dst[i] - lo], 1);
    __syncthreads();

    int a0 = cnt[2 * t], a1 = cnt[2 * t + 1];
    tsum[t] = a0 + a1;
    __syncthreads();
    for (int o = 1; o < 256; o <<= 1) {
        int v = (t >= o) ? tsum[t - o] : 0;
        __syncthreads();
        tsum[t] += v;
        __syncthreads();
    }
    int excl = tsum[t] - (a0 + a1);
    pos[2 * t]     = start + excl;
    pos[2 * t + 1] = start + excl + a0;

    int d0 = lo + 2 * t, d1 = lo + 2 * t + 1;
    if (d0 < hi) { hist[d0] = a0; off[d0] = start + excl + a0; }
    if (d1 < hi) { hist[d1] = a1; off[d1] = start + excl + a0 + a1; }
    __syncthreads();

    for (int i = start + t; i < end; i += 256) {
        int d = tmp_dst[i] - lo;
        int r = atomicAdd(&pos[d], 1);
        edges[r] = tmp_edges[i];
    }
}

// ======================= dtype conversions =======================

__global__ __launch_bounds__(256) void conv_x_kernel(const float* __restrict__ x,
                                                     __hip_bfloat16* __restrict__ xb,
                                                     long long total4) {
    long long i = (long long)blockIdx.x * 256 + threadIdx.x;
    if (i >= total4) return;
    float4 v = reinterpret_cast<const float4*>(x)[i];
    union { ushort4 u; __hip_bfloat162 h2[2]; } o;
    o.h2[0] = __float22bfloat162_rn(make_float2(v.x, v.y));
    o.h2[1] = __float22bfloat162_rn(make_float2(v.z, v.w));
    reinterpret_cast<ushort4*>(xb)[i] = o.u;
}

// Wt[j][k] = (k<128 ? Wrel[k][j] : Wroot[k-128][j]), bf16
template <int DOUT>
__global__ __launch_bounds__(256) void conv_w_kernel(const float* __restrict__ Wrel,
                                                     const float* __restrict__ Wroot,
                                                     __hip_bfloat16* __restrict__ Wt) {
    int idx = blockIdx.x * 256 + threadIdx.x;
    if (idx >= DOUT * 256) return;
    int j = idx >> 8;
    int k = idx & 255;
    float v = (k < 128) ? Wrel[(size_t)k * DOUT + j] : Wroot[(size_t)(k - 128) * DOUT + j];
    Wt[idx] = __float2bfloat16(v);
}

// =============== segmented aggregation v2: 4 edge-slots/wave, 16B/lane ===============
__global__ __launch_bounds__(256) void aggregate_kernel(const __hip_bfloat16* __restrict__ featb,
                                                        const int2* __restrict__ edges,
                                                        const int* __restrict__ off,
                                                        const int* __restrict__ hist,
                                                        __hip_bfloat16* __restrict__ aggb,
                                                        int N) {
    int node = blockIdx.x * 4 + (threadIdx.x >> 6);
    if (node >= N) return;
    const int lane = threadIdx.x & 63;
    const int g = lane >> 4;
    const int sub = lane & 15;
    const int cnt = hist[node];
    const int end = off[node];
    const int start = end - cnt;
    const float inv = 1.0f / fmaxf((float)cnt, 1.0f);

    const ushort* fb = (const ushort*)featb;
    float acc[8] = {0.f, 0.f, 0.f, 0.f, 0.f, 0.f, 0.f, 0.f};

    int e = start + g;
    for (; e + 4 < end; e += 8) {
        int2 e0 = edges[e];
        int2 e1 = edges[e + 4];
        float w0 = __int_as_float(e0.y);
        float w1 = __int_as_float(e1.y);
        u16x8 r0 = *reinterpret_cast<const u16x8*>(fb + (size_t)e0.x * 128 + sub * 8);
        u16x8 r1 = *reinterpret_cast<const u16x8*>(fb + (size_t)e1.x * 128 + sub * 8);
#pragma unroll
        for (int j = 0; j < 8; ++j) {
            acc[j] += w0 * __int_as_float((unsigned)r0[j] << 16)
                    + w1 * __int_as_float((unsigned)r1[j] << 16);
        }
    }
    if (e < end) {
        int2 e0 = edges[e];
        float w0 = __int_as_float(e0.y);
        u16x8 r0 = *reinterpret_cast<const u16x8*>(fb + (size_t)e0.x * 128 + sub * 8);
#pragma unroll
        for (int j = 0; j < 8; ++j)
            acc[j] += w0 * __int_as_float((unsigned)r0[j] << 16);
    }

#pragma unroll
    for (int j = 0; j < 8; ++j) {
        acc[j] += __shfl_xor(acc[j], 16, 64);
        acc[j] += __shfl_xor(acc[j], 32, 64);
    }

    if (g == 0) {
        union { u16x8 u; __hip_bfloat162 h2[4]; } o;
#pragma unroll
        for (int j = 0; j < 4; ++j)
            o.h2[j] = __float22bfloat162_rn(make_float2(acc[2 * j] * inv, acc[2 * j + 1] * inv));
        *reinterpret_cast<u16x8*>((ushort*)aggb + (size_t)node * 128 + sub * 8) = o.u;
    }
}

// =============== MFMA GEMM v3: 128x128 block tile, depth-2 k-pipeline ===============
// out = [Arel|Aroot] @ Wt^T + bias.  Wt: [DOUT][256] bf16.
// __launch_bounds__(256,3): VGPR cap ~170 so the double-buffered a/b frags stay
// in registers and 8+ loads stay in flight per wave (latency -> bandwidth bound).
template <int DOUT, bool OUT_BF16>
__global__ __launch_bounds__(256, 3) void gemm_mfma3(const __hip_bfloat16* __restrict__ Arel,
                                                     const __hip_bfloat16* __restrict__ Aroot,
                                                     const __hip_bfloat16* __restrict__ Wt,
                                                     const float* __restrict__ bias,
                                                     void* __restrict__ outp,
                                                     int M) {
    constexpr int NY = DOUT / 128;
    const int nb = gridDim.x;
    const int orig = blockIdx.x;
    const int xcd = orig & 7;
    const int lid = orig >> 3;
    const int q = nb >> 3, r = nb & 7;
    const int wgid = (xcd < r ? xcd * (q + 1) : r * (q + 1) + (xcd - r) * q) + lid;

    const int ty = wgid % NY;
    const int tx = wgid / NY;
    const int tid = threadIdx.x;
    const int lane = tid & 63;
    const int wave = tid >> 6;
    const int lr = lane & 15;
    const int lk = lane >> 4;
    const int mbase = tx * 128 + (wave >> 1) * 64;
    const int nbase = ty * 128 + (wave & 1) * 64;

    const short* arow[4];
    const short* xrow[4];
#pragma unroll
    for (int mi = 0; mi < 4; ++mi) {
        int row = mbase + mi * 16 + lr;
        int rc = row < M ? row : M - 1;
        arow[mi] = (const short*)Arel  + (size_t)rc * 128 + lk * 8;
        xrow[mi] = (const short*)Aroot + (size_t)rc * 128 + lk * 8;
    }
    const short* wrow[4];
#pragma unroll
    for (int ni = 0; ni < 4; ++ni)
        wrow[ni] = (const short*)Wt + (size_t)(nbase + ni * 16 + lr) * 256 + lk * 8;

    f32x4 zero = {0.f, 0.f, 0.f, 0.f};
    f32x4 acc[4][4];
#pragma unroll
    for (int mi = 0; mi < 4; ++mi)
#pragma unroll
        for (int ni = 0; ni < 4; ++ni) acc[mi][ni] = zero;

    // depth-2 register pipeline over the 8 k-steps
    bf16x8 abuf[2][4], bbuf[2][4];

#define LOADK(KK, P)                                                            \
    {                                                                           \
        _Pragma("unroll")                                                       \
        for (int mi = 0; mi < 4; ++mi)                                          \
            abuf[P][mi] = ((KK) < 4)                                            \
                ? *reinterpret_cast<const bf16x8*>(arow[mi] + (KK) * 32)        \
                : *reinterpret_cast<const bf16x8*>(xrow[mi] + ((KK) - 4) * 32); \
        _Pragma("unroll")                                                       \
        for (int ni = 0; ni < 4; ++ni)                                          \
            bbuf[P][ni] = *reinterpret_cast<const bf16x8*>(wrow[ni] + (KK) * 32); \
    }

    LOADK(0, 0)
#pragma unroll
    for (int kk = 0; kk < 8; ++kk) {
        const int p = kk & 1;
        if (kk < 7) LOADK(kk + 1, (kk + 1) & 1)
#pragma unroll
        for (int mi = 0; mi < 4; ++mi)
#pragma unroll
            for (int ni = 0; ni < 4; ++ni)
                acc[mi][ni] = __builtin_amdgcn_mfma_f32_16x16x32_bf16(abuf[p][mi], bbuf[p][ni], acc[mi][ni], 0, 0, 0);
    }
#undef LOADK

#pragma unroll
    for (int mi = 0; mi < 4; ++mi)
#pragma unroll
        for (int ni = 0; ni < 4; ++ni) {
            int col = nbase + ni * 16 + lr;
            float bv = bias[col];
#pragma unroll
            for (int rr = 0; rr < 4; ++rr) {
                int row = mbase + mi * 16 + lk * 4 + rr;
                if (row < M) {
                    float v = acc[mi][ni][rr] + bv;
                    if (OUT_BF16)
                        ((__hip_bfloat16*)outp)[(size_t)row * DOUT + col] = __float2bfloat16(v);
                    else
                        __builtin_nontemporal_store(v, (float*)outp + (size_t)row * DOUT + col);
                }
            }
        }
}

// ======================= launch =======================

extern "C" void kernel_launch(void* const* d_in, const int* in_sizes, int n_in,
                              void* d_out, int out_size, void* d_ws, size_t ws_size,
                              hipStream_t stream) {
    const float* x      = (const float*)d_in[0];
    const int*   ei     = (const int*)d_in[1];
    const float* ew     = (const float*)d_in[2];
    const float* Wrel1  = (const float*)d_in[3];
    const float* b1     = (const float*)d_in[4];
    const float* Wroot1 = (const float*)d_in[5];
    const float* Wrel2  = (const float*)d_in[6];
    const float* b2     = (const float*)d_in[7];
    const float* Wroot2 = (const float*)d_in[8];
    float* out = (float*)d_out;

    const int N = in_sizes[0] / D_IN;
    const long long E = in_sizes[2];
    const int* src = ei;
    const int* dst = ei + E;

    const int nbe = (int)((E + SORT_CHUNK - 1) / SORT_CHUNK);
    const int M = nbe * NBUCK;
    const int nbM = (M + 1023) / 1024;

    int* hist = (int*)d_ws;
    int* off  = hist + N;
    int* part = off + N;
    int2* edges = (int2*)(part + 128);
    __hip_bfloat16* agg1b = (__hip_bfloat16*)(edges + E);
    __hip_bfloat16* xb    = agg1b + (size_t)N * D_IN;
    __hip_bfloat16* agg2b = xb    + (size_t)N * D_IN;
    __hip_bfloat16* hb    = agg2b + (size_t)N * D_IN;
    __hip_bfloat16* Wt1   = hb    + (size_t)N * D_IN;
    __hip_bfloat16* Wt2   = Wt1   + 128 * 256;

    // transient sort buffers overlapped into agg regions (consumed before aggregates run)
    int* bh      = (int*)agg1b;
    int* S       = bh + M;
    int* tmp_dst = S + M;
    int2* tmp_edges = (int2*)agg2b;

    // ---- sort edges by dst ----
    bucket_hist_kernel<<<nbe, 256, 0, stream>>>(dst, bh, E, N, nbe);
    scan_block_sums<<<nbM, 256, 0, stream>>>(bh, part, M);
    scan_partials<<<1, 64, 0, stream>>>(part, nbM);
    scan_final<<<nbM, 256, 0, stream>>>(bh, part, S, M);
    bucket_scatter_kernel<<<nbe, 256, 0, stream>>>(src, dst, ew, S, tmp_edges, tmp_dst, E, N, nbe);
    bucket_sort_kernel<<<NBUCK, 256, 0, stream>>>(S, tmp_edges, tmp_dst, edges, hist, off, E, N, nbe);

    // ---- conversions ----
    {
        long long total4 = (long long)N * D_IN / 4;
        conv_x_kernel<<<(int)((total4 + 255) / 256), 256, 0, stream>>>(x, xb, total4);
        conv_w_kernel<128><<<(128 * 256 + 255) / 256, 256, 0, stream>>>(Wrel1, Wroot1, Wt1);
        conv_w_kernel<256><<<(256 * 256 + 255) / 256, 256, 0, stream>>>(Wrel2, Wroot2, Wt2);
    }

    const int ab = (N + 3) / 4;
    const int gx = (N + 127) / 128;

    // ---- layer 1 ----
    aggregate_kernel<<<ab, 256, 0, stream>>>(xb, edges, off, hist, agg1b, N);
    gemm_mfma3<128, true><<<gx * 1, 256, 0, stream>>>(agg1b, xb, Wt1, b1, hb, N);

    // ---- layer 2 ----
    aggregate_kernel<<<ab, 256, 0, stream>>>(hb, edges, off, hist, agg2b, N);
    gemm_mfma3<256, false><<<gx * 2, 256, 0, stream>>>(agg2b, hb, Wt2, b2, out, N);
}

// Round 10
// 300.031 us; speedup vs baseline: 1.5222x; 1.0843x over previous
//
#include <hip/hip_runtime.h>
#include <hip/hip_bf16.h>

#define D_IN 128
#define SORT_CHUNK 4096
#define NBUCK 256

typedef __attribute__((ext_vector_type(8))) short bf16x8;
typedef __attribute__((ext_vector_type(8))) unsigned short u16x8;
typedef __attribute__((ext_vector_type(4))) float f32x4;

// ======================= generic exclusive scan (1024/block) =======================

__global__ __launch_bounds__(256) void scan_block_sums(const int* __restrict__ in,
                                                       int* __restrict__ partial,
                                                       int M) {
    __shared__ int sdata[256];
    int b = blockIdx.x, t = threadIdx.x;
    int base = b * 1024 + t * 4;
    int s = 0;
#pragma unroll
    for (int i = 0; i < 4; ++i) {
        int idx = base + i;
        if (idx < M) s += in[idx];
    }
    sdata[t] = s;
    __syncthreads();
    for (int off = 128; off > 0; off >>= 1) {
        if (t < off) sdata[t] += sdata[t + off];
        __syncthreads();
    }
    if (t == 0) partial[b] = sdata[0];
}

__global__ void scan_partials(int* __restrict__ partial, int nb) {
    if (threadIdx.x == 0 && blockIdx.x == 0) {
        int run = 0;
        for (int i = 0; i < nb; ++i) {
            int t = partial[i];
            partial[i] = run;
            run += t;
        }
    }
}

__global__ __launch_bounds__(256) void scan_final(const int* __restrict__ in,
                                                  const int* __restrict__ partial,
                                                  int* __restrict__ outS,
                                                  int M) {
    __shared__ int sdata[256];
    int b = blockIdx.x, t = threadIdx.x;
    int base = b * 1024 + t * 4;
    int v[4];
    int s = 0;
#pragma unroll
    for (int i = 0; i < 4; ++i) {
        int idx = base + i;
        v[i] = (idx < M) ? in[idx] : 0;
        s += v[i];
    }
    sdata[t] = s;
    __syncthreads();
    for (int o = 1; o < 256; o <<= 1) {
        int tmp = 0;
        if (t >= o) tmp = sdata[t - o];
        __syncthreads();
        sdata[t] += tmp;
        __syncthreads();
    }
    int run = partial[b] + (sdata[t] - s);
#pragma unroll
    for (int i = 0; i < 4; ++i) {
        int idx = base + i;
        if (idx < M) outS[idx] = run;
        run += v[i];
    }
}

// ======================= two-pass bucket sort by dst =======================

__global__ __launch_bounds__(256) void bucket_hist_kernel(const int* __restrict__ dst,
                                                          int* __restrict__ bh,
                                                          long long E, int N, int nbe) {
    __shared__ int cnt[NBUCK];
    cnt[threadIdx.x] = 0;
    __syncthreads();
    long long base = (long long)blockIdx.x * SORT_CHUNK;
    long long end = base + SORT_CHUNK;
    if (end > E) end = E;
    for (long long i = base + threadIdx.x; i < end; i += 256) {
        int b = (int)(((long long)dst[i] << 8) / N);
        atomicAdd(&cnt[b], 1);
    }
    __syncthreads();
    bh[threadIdx.x * nbe + blockIdx.x] = cnt[threadIdx.x];
}

__global__ __launch_bounds__(256) void bucket_scatter_kernel(const int* __restrict__ src,
                                                             const int* __restrict__ dst,
                                                             const float* __restrict__ ew,
                                                             const int* __restrict__ S,
                                                             int2* __restrict__ tmp_edges,
                                                             int* __restrict__ tmp_dst,
                                                             long long E, int N, int nbe) {
    __shared__ int base_lds[NBUCK];
    __shared__ int cnt[NBUCK];
    base_lds[threadIdx.x] = S[threadIdx.x * nbe + blockIdx.x];
    cnt[threadIdx.x] = 0;
    __syncthreads();
    long long b0 = (long long)blockIdx.x * SORT_CHUNK;
    long long e1 = b0 + SORT_CHUNK;
    if (e1 > E) e1 = E;
    for (long long i = b0 + threadIdx.x; i < e1; i += 256) {
        int d = dst[i];
        int b = (int)(((long long)d << 8) / N);
        int p = base_lds[b] + atomicAdd(&cnt[b], 1);
        tmp_edges[p] = make_int2(src[i], __float_as_int(ew[i]));
        tmp_dst[p] = d;
    }
}

__global__ __launch_bounds__(256) void bucket_sort_kernel(const int* __restrict__ S,
                                                          const int2* __restrict__ tmp_edges,
                                                          const int* __restrict__ tmp_dst,
                                                          int2* __restrict__ edges,
                                                          int* __restrict__ hist,
                                                          int* __restrict__ off,
                                                          long long E, int N, int nbe) {
    __shared__ int cnt[512];
    __shared__ int tsum[256];
    __shared__ int pos[512];
    const int b = blockIdx.x, t = threadIdx.x;
    const int lo = (int)(((long long)b * N + 255) >> 8);
    const int hi = (int)(((long long)(b + 1) * N + 255) >> 8);
    const int start = S[b * nbe];
    const int end = (b == NBUCK - 1) ? (int)E : S[(b + 1) * nbe];

    cnt[t] = 0;
    cnt[t + 256] = 0;
    __syncthreads();
    for (int i = start + t; i < end; i += 256)
        atomicAdd(&cnt[tmp_dst[i] - lo], 1);
    __syncthreads();

    int a0 = cnt[2 * t], a1 = cnt[2 * t + 1];
    tsum[t] = a0 + a1;
    __syncthreads();
    for (int o = 1; o < 256; o <<= 1) {
        int v = (t >= o) ? tsum[t - o] : 0;
        __syncthreads();
        tsum[t] += v;
        __syncthreads();
    }
    int excl = tsum[t] - (a0 + a1);
    pos[2 * t]     = start + excl;
    pos[2 * t + 1] = start + excl + a0;

    int d0 = lo + 2 * t, d1 = lo + 2 * t + 1;
    if (d0 < hi) { hist[d0] = a0; off[d0] = start + excl + a0; }
    if (d1 < hi) { hist[d1] = a1; off[d1] = start + excl + a0 + a1; }
    __syncthreads();

    for (int i = start + t; i < end; i += 256) {
        int d = tmp_dst[i] - lo;
        int r = atomicAdd(&pos[d], 1);
        edges[r] = tmp_edges[i];
    }
}

// ======================= dtype conversions =======================

__global__ __launch_bounds__(256) void conv_x_kernel(const float* __restrict__ x,
                                                     __hip_bfloat16* __restrict__ xb,
                                                     long long total4) {
    long long i = (long long)blockIdx.x * 256 + threadIdx.x;
    if (i >= total4) return;
    float4 v = reinterpret_cast<const float4*>(x)[i];
    union { ushort4 u; __hip_bfloat162 h2[2]; } o;
    o.h2[0] = __float22bfloat162_rn(make_float2(v.x, v.y));
    o.h2[1] = __float22bfloat162_rn(make_float2(v.z, v.w));
    reinterpret_cast<ushort4*>(xb)[i] = o.u;
}

// Wt[j][k] = (k<128 ? Wrel[k][j] : Wroot[k-128][j]), bf16
template <int DOUT>
__global__ __launch_bounds__(256) void conv_w_kernel(const float* __restrict__ Wrel,
                                                     const float* __restrict__ Wroot,
                                                     __hip_bfloat16* __restrict__ Wt) {
    int idx = blockIdx.x * 256 + threadIdx.x;
    if (idx >= DOUT * 256) return;
    int j = idx >> 8;
    int k = idx & 255;
    float v = (k < 128) ? Wrel[(size_t)k * DOUT + j] : Wroot[(size_t)(k - 128) * DOUT + j];
    Wt[idx] = __float2bfloat16(v);
}

// =============== segmented aggregation v2: 4 edge-slots/wave, 16B/lane ===============
__global__ __launch_bounds__(256) void aggregate_kernel(const __hip_bfloat16* __restrict__ featb,
                                                        const int2* __restrict__ edges,
                                                        const int* __restrict__ off,
                                                        const int* __restrict__ hist,
                                                        __hip_bfloat16* __restrict__ aggb,
                                                        int N) {
    int node = blockIdx.x * 4 + (threadIdx.x >> 6);
    if (node >= N) return;
    const int lane = threadIdx.x & 63;
    const int g = lane >> 4;
    const int sub = lane & 15;
    const int cnt = hist[node];
    const int end = off[node];
    const int start = end - cnt;
    const float inv = 1.0f / fmaxf((float)cnt, 1.0f);

    const ushort* fb = (const ushort*)featb;
    float acc[8] = {0.f, 0.f, 0.f, 0.f, 0.f, 0.f, 0.f, 0.f};

    int e = start + g;
    for (; e + 4 < end; e += 8) {
        int2 e0 = edges[e];
        int2 e1 = edges[e + 4];
        float w0 = __int_as_float(e0.y);
        float w1 = __int_as_float(e1.y);
        u16x8 r0 = *reinterpret_cast<const u16x8*>(fb + (size_t)e0.x * 128 + sub * 8);
        u16x8 r1 = *reinterpret_cast<const u16x8*>(fb + (size_t)e1.x * 128 + sub * 8);
#pragma unroll
        for (int j = 0; j < 8; ++j) {
            acc[j] += w0 * __int_as_float((unsigned)r0[j] << 16)
                    + w1 * __int_as_float((unsigned)r1[j] << 16);
        }
    }
    if (e < end) {
        int2 e0 = edges[e];
        float w0 = __int_as_float(e0.y);
        u16x8 r0 = *reinterpret_cast<const u16x8*>(fb + (size_t)e0.x * 128 + sub * 8);
#pragma unroll
        for (int j = 0; j < 8; ++j)
            acc[j] += w0 * __int_as_float((unsigned)r0[j] << 16);
    }

#pragma unroll
    for (int j = 0; j < 8; ++j) {
        acc[j] += __shfl_xor(acc[j], 16, 64);
        acc[j] += __shfl_xor(acc[j], 32, 64);
    }

    if (g == 0) {
        union { u16x8 u; __hip_bfloat162 h2[4]; } o;
#pragma unroll
        for (int j = 0; j < 4; ++j)
            o.h2[j] = __float22bfloat162_rn(make_float2(acc[2 * j] * inv, acc[2 * j + 1] * inv));
        *reinterpret_cast<u16x8*>((ushort*)aggb + (size_t)node * 128 + sub * 8) = o.u;
    }
}

// =============== MFMA GEMM v4: B staged in LDS (XOR-swizzled), A prefetched ===============
// out = [Arel|Aroot] @ Wt^T + bias.  Wt: [DOUT][256] bf16.
// Block 256 thr / 4 waves, tile 128 rows x 128 cols.
// B-tile (128 cols x 256 k = 64 KB) staged ONCE via global_load_lds with the
// T2 XOR baked into the SOURCE address (LDS dest stays linear, rule 21):
//   LDS[col*512 + off] = Wt_row_col[ off ^ ((col&7)<<4) ]
// ds_read applies the same XOR -> 8 distinct 16B slots per 8 lanes (2-way, free).
// A frags (32 x 16B) issued as one burst after the barrier; k-loop is LDS+MFMA only.
template <int DOUT, bool OUT_BF16>
__global__ __launch_bounds__(256, 2) void gemm_mfma4(const __hip_bfloat16* __restrict__ Arel,
                                                     const __hip_bfloat16* __restrict__ Aroot,
                                                     const __hip_bfloat16* __restrict__ Wt,
                                                     const float* __restrict__ bias,
                                                     void* __restrict__ outp,
                                                     int M) {
    constexpr int NY = DOUT / 128;
    __shared__ __align__(16) unsigned char Bs[65536];

    const int nb = gridDim.x;
    const int orig = blockIdx.x;
    const int xcd = orig & 7;
    const int lid = orig >> 3;
    const int q = nb >> 3, r = nb & 7;
    const int wgid = (xcd < r ? xcd * (q + 1) : r * (q + 1) + (xcd - r) * q) + lid;

    const int ty = wgid % NY;
    const int tx = wgid / NY;
    const int tid = threadIdx.x;
    const int lane = tid & 63;
    const int wave = tid >> 6;
    const int lr = lane & 15;
    const int lk = lane >> 4;

    // ---- stage B tile: 4096 x 16B slots, swizzled source ----
    const char* wbase = (const char*)(Wt + (size_t)ty * 128 * 256);
#pragma unroll
    for (int i = 0; i < 16; ++i) {
        int s = i * 256 + tid;              // 16B slot index
        int col = s >> 5;                   // strip-local output col
        int off16 = s & 31;                 // 16B unit within the col's 512B row
        int g16 = col * 32 + (off16 ^ (col & 7));
        __builtin_amdgcn_global_load_lds(
            (const __attribute__((address_space(1))) unsigned int*)(wbase + (size_t)g16 * 16),
            (__attribute__((address_space(3))) unsigned int*)(&Bs[s * 16]),
            16, 0, 0);
    }

    const int mbase = tx * 128 + (wave >> 1) * 64;
    const int nwave = (wave & 1) * 64;      // strip-local col base of this wave
    const int nbase = ty * 128 + nwave;     // global col base

    const short* arow[4];
    const short* xrow[4];
#pragma unroll
    for (int mi = 0; mi < 4; ++mi) {
        int row = mbase + mi * 16 + lr;
        int rc = row < M ? row : M - 1;
        arow[mi] = (const short*)Arel  + (size_t)rc * 128 + lk * 8;
        xrow[mi] = (const short*)Aroot + (size_t)rc * 128 + lk * 8;
    }

    __syncthreads();   // drains the global_load_lds (compiler emits vmcnt(0) before barrier)

    // ---- burst-prefetch all A fragments (32 x 16B in flight per lane) ----
    bf16x8 abuf[8][4];
#pragma unroll
    for (int kk = 0; kk < 8; ++kk)
#pragma unroll
        for (int mi = 0; mi < 4; ++mi)
            abuf[kk][mi] = (kk < 4)
                ? *reinterpret_cast<const bf16x8*>(arow[mi] + kk * 32)
                : *reinterpret_cast<const bf16x8*>(xrow[mi] + (kk - 4) * 32);

    f32x4 zero = {0.f, 0.f, 0.f, 0.f};
    f32x4 acc[4][4];
#pragma unroll
    for (int mi = 0; mi < 4; ++mi)
#pragma unroll
        for (int ni = 0; ni < 4; ++ni) acc[mi][ni] = zero;

    // ---- k-loop: LDS reads + MFMA only ----
#pragma unroll
    for (int kk = 0; kk < 8; ++kk) {
        bf16x8 b[4];
#pragma unroll
        for (int ni = 0; ni < 4; ++ni) {
            int c = nwave + ni * 16 + lr;
            int byteoff = c * 512 + ((kk * 64 + lk * 16) ^ ((c & 7) << 4));
            b[ni] = *reinterpret_cast<const bf16x8*>(&Bs[byteoff]);
        }
#pragma unroll
        for (int mi = 0; mi < 4; ++mi)
#pragma unroll
            for (int ni = 0; ni < 4; ++ni)
                acc[mi][ni] = __builtin_amdgcn_mfma_f32_16x16x32_bf16(abuf[kk][mi], b[ni], acc[mi][ni], 0, 0, 0);
    }

    // ---- epilogue ----
#pragma unroll
    for (int mi = 0; mi < 4; ++mi)
#pragma unroll
        for (int ni = 0; ni < 4; ++ni) {
            int col = nbase + ni * 16 + lr;
            float bv = bias[col];
#pragma unroll
            for (int rr = 0; rr < 4; ++rr) {
                int row = mbase + mi * 16 + lk * 4 + rr;
                if (row < M) {
                    float v = acc[mi][ni][rr] + bv;
                    if (OUT_BF16)
                        ((__hip_bfloat16*)outp)[(size_t)row * DOUT + col] = __float2bfloat16(v);
                    else
                        __builtin_nontemporal_store(v, (float*)outp + (size_t)row * DOUT + col);
                }
            }
        }
}

// ======================= launch =======================

extern "C" void kernel_launch(void* const* d_in, const int* in_sizes, int n_in,
                              void* d_out, int out_size, void* d_ws, size_t ws_size,
                              hipStream_t stream) {
    const float* x      = (const float*)d_in[0];
    const int*   ei     = (const int*)d_in[1];
    const float* ew     = (const float*)d_in[2];
    const float* Wrel1  = (const float*)d_in[3];
    const float* b1     = (const float*)d_in[4];
    const float* Wroot1 = (const float*)d_in[5];
    const float* Wrel2  = (const float*)d_in[6];
    const float* b2     = (const float*)d_in[7];
    const float* Wroot2 = (const float*)d_in[8];
    float* out = (float*)d_out;

    const int N = in_sizes[0] / D_IN;
    const long long E = in_sizes[2];
    const int* src = ei;
    const int* dst = ei + E;

    const int nbe = (int)((E + SORT_CHUNK - 1) / SORT_CHUNK);
    const int M = nbe * NBUCK;
    const int nbM = (M + 1023) / 1024;

    int* hist = (int*)d_ws;
    int* off  = hist + N;
    int* part = off + N;
    int2* edges = (int2*)(part + 128);
    __hip_bfloat16* agg1b = (__hip_bfloat16*)(edges + E);
    __hip_bfloat16* xb    = agg1b + (size_t)N * D_IN;
    __hip_bfloat16* agg2b = xb    + (size_t)N * D_IN;
    __hip_bfloat16* hb    = agg2b + (size_t)N * D_IN;
    __hip_bfloat16* Wt1   = hb    + (size_t)N * D_IN;
    __hip_bfloat16* Wt2   = Wt1   + 128 * 256;

    // transient sort buffers overlapped into agg regions (consumed before aggregates run)
    int* bh      = (int*)agg1b;
    int* S       = bh + M;
    int* tmp_dst = S + M;
    int2* tmp_edges = (int2*)agg2b;

    // ---- sort edges by dst ----
    bucket_hist_kernel<<<nbe, 256, 0, stream>>>(dst, bh, E, N, nbe);
    scan_block_sums<<<nbM, 256, 0, stream>>>(bh, part, M);
    scan_partials<<<1, 64, 0, stream>>>(part, nbM);
    scan_final<<<nbM, 256, 0, stream>>>(bh, part, S, M);
    bucket_scatter_kernel<<<nbe, 256, 0, stream>>>(src, dst, ew, S, tmp_edges, tmp_dst, E, N, nbe);
    bucket_sort_kernel<<<NBUCK, 256, 0, stream>>>(S, tmp_edges, tmp_dst, edges, hist, off, E, N, nbe);

    // ---- conversions ----
    {
        long long total4 = (long long)N * D_IN / 4;
        conv_x_kernel<<<(int)((total4 + 255) / 256), 256, 0, stream>>>(x, xb, total4);
        conv_w_kernel<128><<<(128 * 256 + 255) / 256, 256, 0, stream>>>(Wrel1, Wroot1, Wt1);
        conv_w_kernel<256><<<(256 * 256 + 255) / 256, 256, 0, stream>>>(Wrel2, Wroot2, Wt2);
    }

    const int ab = (N + 3) / 4;
    const int gx = (N + 127) / 128;

    // ---- layer 1 ----
    aggregate_kernel<<<ab, 256, 0, stream>>>(xb, edges, off, hist, agg1b, N);
    gemm_mfma4<128, true><<<gx * 1, 256, 0, stream>>>(agg1b, xb, Wt1, b1, hb, N);

    // ---- layer 2 ----
    aggregate_kernel<<<ab, 256, 0, stream>>>(hb, edges, off, hist, agg2b, N);
    gemm_mfma4<256, false><<<gx * 2, 256, 0, stream>>>(agg2b, hb, Wt2, b2, out, N);
}